// Round 13
// baseline (671.844 us; speedup 1.0000x reference)
//
#include <hip/hip_runtime.h>

#define N_NODES 65536
#define NSEG    128

using s16x8 = __attribute__((ext_vector_type(8))) short;
using s16x4 = __attribute__((ext_vector_type(4))) short;
using f32x4 = __attribute__((ext_vector_type(4))) float;
using u32x2 = __attribute__((ext_vector_type(2))) unsigned;

__device__ __forceinline__ float bf2f(unsigned short s) {
    union { unsigned u; float f; } x; x.u = ((unsigned)s) << 16; return x.f;
}
__device__ __forceinline__ short f2bf(float f) {
    union { float f; unsigned u; } x; x.f = f;
    unsigned r = x.u + 0x7FFFu + ((x.u >> 16) & 1u);
    return (short)(r >> 16);
}
__device__ __forceinline__ unsigned cvtpk(float a, float b) {   // packed bf16(a)|bf16(b)<<16
    unsigned r;
    asm("v_cvt_pk_bf16_f32 %0, %1, %2" : "=v"(r) : "v"(a), "v"(b));
    return r;
}
__device__ __forceinline__ void gload_lds16(const void* g, void* lds) {
    __builtin_amdgcn_global_load_lds((const __attribute__((address_space(1))) void*)g,
                                     (__attribute__((address_space(3))) void*)lds, 16, 0, 0);
}

// ---------------- prep kernels ----------------

__global__ void prep_sm_kernel(const float* __restrict__ score, const float* __restrict__ pos,
                               short* __restrict__ sm) {
    int i = blockIdx.x * blockDim.x + threadIdx.x;
    int base = i * 4;
    f32x4 s = __builtin_nontemporal_load((const f32x4*)(score + base));
    f32x4 p = *(const f32x4*)(pos + (base & 255));
    s16x4 o;
#pragma unroll
    for (int j = 0; j < 4; ++j) o[j] = f2bf(s[j] + p[j]);
    *(s16x4*)(sm + base) = o;
}

// all weight transposes in ONE launch. fp32 [R][C] -> bf16 [C][R] tiles of 32x32.
__global__ void transpose_all_kernel(const float* __restrict__ Wq1, const float* __restrict__ Wk1,
                                     const float* __restrict__ Wv1, const float* __restrict__ Wq2,
                                     const float* __restrict__ Wk2, const float* __restrict__ Wv2,
                                     const float* __restrict__ Wo1, const float* __restrict__ Wo2,
                                     short* __restrict__ W1T, short* __restrict__ W2T,
                                     short* __restrict__ Wo1T, short* __restrict__ Wo2T) {
    int t = blockIdx.x;
    const float* in; short* out; int R, C, tx, ty;
    if (t < 1536) {            // W1: 24 units, 256x256, 8x8 tiles
        int u = t >> 6, rem = t & 63;
        const float* s = (u < 8) ? Wq1 : (u < 16) ? Wk1 : Wv1;
        in = s + (long)(u & 7) * 65536; out = W1T + (long)u * 65536;
        R = 256; C = 256; tx = rem & 7; ty = rem >> 3;
    } else if (t < 2304) {     // W2: 24 units, 256x128, 4x8 tiles
        int t2 = t - 1536, u = t2 >> 5, rem = t2 & 31;
        const float* s = (u < 8) ? Wq2 : (u < 16) ? Wk2 : Wv2;
        in = s + (long)(u & 7) * 32768; out = W2T + (long)u * 32768;
        R = 256; C = 128; tx = rem & 3; ty = rem >> 2;
    } else if (t < 2560) {     // Wo1: 1024x256, 8x32 tiles
        int t3 = t - 2304;
        in = Wo1; out = Wo1T; R = 1024; C = 256; tx = t3 & 7; ty = t3 >> 3;
    } else {                   // Wo2: 256x128, 4x8 tiles
        int t4 = t - 2560;
        in = Wo2; out = Wo2T; R = 256; C = 128; tx = t4 & 3; ty = t4 >> 2;
    }
    __shared__ float tbuf[32][33];
    const int c0 = tx * 32, r0 = ty * 32;
    const int lx = threadIdx.x & 31, ly = threadIdx.x >> 5;
#pragma unroll
    for (int i = 0; i < 32; i += 8)
        tbuf[ly + i][lx] = in[(long)(r0 + ly + i) * C + c0 + lx];
    __syncthreads();
#pragma unroll
    for (int i = 0; i < 32; i += 8)
        out[(long)(c0 + ly + i) * R + r0 + lx] = f2bf(tbuf[lx][ly + i]);
}

__global__ void prep_small_kernel(const float* __restrict__ bq1, const float* __restrict__ bk1,
                                  const float* __restrict__ bv1, const float* __restrict__ bq2,
                                  const float* __restrict__ bk2, const float* __restrict__ bv2,
                                  const float* __restrict__ bo2, const float* __restrict__ para,
                                  float* __restrict__ b1cat, float* __restrict__ b2cat,
                                  float* __restrict__ bo2p) {
    int i = blockIdx.x * blockDim.x + threadIdx.x;
    if (i < 6144) {
        int u = i >> 8, j = i & 255;
        const float* s = (u < 8) ? (bq1 + u * 256 + j)
                       : (u < 16) ? (bk1 + (u - 8) * 256 + j)
                                  : (bv1 + (u - 16) * 256 + j);
        b1cat[i] = *s;
    } else if (i < 9216) {
        int ii = i - 6144;
        int u = ii >> 7, j = ii & 127;
        const float* s = (u < 8) ? (bq2 + u * 128 + j)
                       : (u < 16) ? (bk2 + (u - 8) * 128 + j)
                                  : (bv2 + (u - 16) * 128 + j);
        b2cat[ii] = *s;
    } else if (i < 9344) {
        int e = i - 9216;
        bo2p[e] = bo2[e] + para[e];
    }
}

// ------- fused 2-layer MLP (r10 control + cvt_pk); 512 threads (8 waves), 48 KB -------
template <bool OUTBF16>
__global__ __launch_bounds__(512, 2)
void fused_mlp(const short* __restrict__ A, int lda,
               const short* __restrict__ B1, long b1_ustride,    // [256, K1]
               const float* __restrict__ bias1, int bias1_ustride,
               const short* __restrict__ B2, long b2_ustride,    // [128, 256]
               const float* __restrict__ bias2, int bias2_ustride,
               void* __restrict__ Cv, int ldc, long c_ustride, int K1) {
    const int u = blockIdx.y;
    B1    += (long)u * b1_ustride;
    bias1 += (long)u * bias1_ustride;
    B2    += (long)u * b2_ustride;
    bias2 += (long)u * bias2_ustride;

    __shared__ __align__(16) short lds[24576];   // 48 KB
    short* Bs = lds;            // [128][64] W-tile — disjoint from hs
    short* As = lds + 8192;     // [128][64] A-tile (aliased by hs)
    short* hs = lds + 8192;     // [128][128] h-slab, chunk-XOR swizzled

    const int tid = threadIdx.x, lane = tid & 63, wave = tid >> 6;   // 8 waves
    const int wm = wave >> 2;          // node half
    const int wn = wave & 3;           // 32-col quarter
    const int brow = blockIdx.x * 128;

    const int lrow = lane >> 3;
    const int schk = ((lane & 7) ^ lrow) * 8;
    const int nkt1 = K1 >> 6;
    const int l15 = lane & 15, lq = lane >> 4;

    f32x4 acc2[4][2];
#pragma unroll
    for (int i = 0; i < 4; ++i)
#pragma unroll
        for (int j = 0; j < 2; ++j) acc2[i][j] = (f32x4){0.f, 0.f, 0.f, 0.f};

    for (int p = 0; p < 2; ++p) {
        f32x4 acc1[4][2];
#pragma unroll
        for (int i = 0; i < 4; ++i)
#pragma unroll
            for (int j = 0; j < 2; ++j) acc1[i][j] = (f32x4){0.f, 0.f, 0.f, 0.f};

        for (int kt = 0; kt < nkt1; ++kt) {
            __syncthreads();
            const int ko = kt * 64;
#pragma unroll
            for (int i = 0; i < 2; ++i) {
                int cch = wave * 2 + i;
                int r = cch * 8 + lrow;
                gload_lds16(A  + (long)(brow + r) * lda + ko + schk, &As[cch * 512]);
                gload_lds16(B1 + (long)(p * 128 + r) * K1 + ko + schk, &Bs[cch * 512]);
            }
            __syncthreads();
#pragma unroll
            for (int kk = 0; kk < 2; ++kk) {
                const int slot = (((kk * 4) + lq) ^ (lane & 7)) * 8;
                s16x8 af[4], bfv[2];
#pragma unroll
                for (int i = 0; i < 4; ++i)
                    af[i] = *(const s16x8*)&As[(wm * 64 + i * 16 + l15) * 64 + slot];
#pragma unroll
                for (int j = 0; j < 2; ++j)
                    bfv[j] = *(const s16x8*)&Bs[(wn * 32 + j * 16 + l15) * 64 + slot];
#pragma unroll
                for (int i = 0; i < 4; ++i)
#pragma unroll
                    for (int j = 0; j < 2; ++j)
                        acc1[i][j] = __builtin_amdgcn_mfma_f32_16x16x32_bf16(bfv[j], af[i], acc1[i][j], 0, 0, 0);
            }
        }

        __syncthreads();      // GEMM1 reads done

#pragma unroll
        for (int i = 0; i < 2; ++i) {
            int cch = wave * 2 + i;
            int r = cch * 8 + lrow;
            gload_lds16(B2 + (long)r * 256 + p * 128 + schk, &Bs[cch * 512]);
        }

        {
            const int cbq = lq << 2;
#pragma unroll
            for (int j = 0; j < 2; ++j) {
                int cb = wn * 32 + j * 16 + cbq;
                f32x4 bv = *(const f32x4*)(bias1 + p * 128 + cb);
#pragma unroll
                for (int i = 0; i < 4; ++i) {
                    int node = wm * 64 + i * 16 + l15;
                    float t0 = fmaxf(acc1[i][j][0] + bv[0], 0.f);
                    float t1 = fmaxf(acc1[i][j][1] + bv[1], 0.f);
                    float t2 = fmaxf(acc1[i][j][2] + bv[2], 0.f);
                    float t3 = fmaxf(acc1[i][j][3] + bv[3], 0.f);
                    u32x2 hw; hw[0] = cvtpk(t0, t1); hw[1] = cvtpk(t2, t3);
                    *(u32x2*)&hs[node * 128 + (((cb >> 3) ^ (node & 7)) << 3) + (cb & 7)] = hw;
                }
            }
        }

#pragma unroll
        for (int kt2 = 0; kt2 < 2; ++kt2) {
            __syncthreads();
#pragma unroll
            for (int kk = 0; kk < 2; ++kk) {
                const int slotb = (((kk * 4) + lq) ^ (lane & 7)) * 8;
                s16x8 hf[4], wf[2];
#pragma unroll
                for (int i = 0; i < 4; ++i) {
                    int row = wm * 64 + i * 16 + l15;
                    int c = kt2 * 8 + kk * 4 + lq;
                    hf[i] = *(const s16x8*)&hs[row * 128 + ((c ^ (row & 7)) << 3)];
                }
#pragma unroll
                for (int j = 0; j < 2; ++j)
                    wf[j] = *(const s16x8*)&Bs[(wn * 32 + j * 16 + l15) * 64 + slotb];
#pragma unroll
                for (int i = 0; i < 4; ++i)
#pragma unroll
                    for (int j = 0; j < 2; ++j)
                        acc2[i][j] = __builtin_amdgcn_mfma_f32_16x16x32_bf16(wf[j], hf[i], acc2[i][j], 0, 0, 0);
            }
            if (kt2 == 0) {
                __syncthreads();
#pragma unroll
                for (int i = 0; i < 2; ++i) {
                    int cch = wave * 2 + i;
                    int r = cch * 8 + lrow;
                    gload_lds16(B2 + (long)r * 256 + p * 128 + 64 + schk, &Bs[cch * 512]);
                }
            }
        }
    }

    const int cbq = lq << 2;
    if (OUTBF16) {
        __syncthreads();
        short* Cs = hs;
#pragma unroll
        for (int j = 0; j < 2; ++j) {
            int cb = wn * 32 + j * 16 + cbq;
            f32x4 bv = *(const f32x4*)(bias2 + cb);
#pragma unroll
            for (int i = 0; i < 4; ++i) {
                int node = wm * 64 + i * 16 + l15;
                u32x2 ow;
                ow[0] = cvtpk(acc2[i][j][0] + bv[0], acc2[i][j][1] + bv[1]);
                ow[1] = cvtpk(acc2[i][j][2] + bv[2], acc2[i][j][3] + bv[3]);
                *(u32x2*)&Cs[node * 128 + (((cb >> 3) ^ (node & 7)) << 3) + (cb & 7)] = ow;
            }
        }
        __syncthreads();
        short* cbase = (short*)Cv + u * c_ustride + (long)brow * ldc;
#pragma unroll
        for (int p8 = 0; p8 < 4; ++p8) {
            int g = tid + p8 * 512;
            int row = g >> 4, ck = g & 15;
            s16x8 val = *(const s16x8*)&Cs[row * 128 + ((ck ^ (row & 7)) * 8)];
            *(s16x8*)(cbase + (long)row * ldc + ck * 8) = val;
        }
    } else {
        float* cbase = (float*)Cv + u * c_ustride;
#pragma unroll
        for (int j = 0; j < 2; ++j) {
            int cb = wn * 32 + j * 16 + cbq;
            f32x4 bv = *(const f32x4*)(bias2 + cb);
#pragma unroll
            for (int i = 0; i < 4; ++i) {
                int node = wm * 64 + i * 16 + l15;
                f32x4 o;
#pragma unroll
                for (int r = 0; r < 4; ++r) o[r] = acc2[i][j][r] + bv[r];
                *(f32x4*)&cbase[(long)(brow + node) * ldc + cb] = o;
            }
        }
    }
}

// ------- VARIANT fused_mlpB: B1/W2 direct-from-L2 fragments; A-tile BK=32 dbuf -------
// LDS 48 KB: Aa 8K | Ab 8K | hs 32K. One barrier per K-step, all A-stages overlapped;
// GEMM2 barrier-free. Each weight fragment row = one 64B cacheline (L2-resident).
// acc = 64 regs -> within the {48KB, ~128 VGPR} envelope (r11/r12 lessons).
template <bool OUTBF16>
__global__ __launch_bounds__(512, 2)
void fused_mlpB(const short* __restrict__ A, int lda,
                const short* __restrict__ B1, long b1_ustride,    // [256, K1]
                const float* __restrict__ bias1, int bias1_ustride,
                const short* __restrict__ B2, long b2_ustride,    // [128, 256]
                const float* __restrict__ bias2, int bias2_ustride,
                void* __restrict__ Cv, int ldc, long c_ustride, int K1) {
    const int u = blockIdx.y;
    B1    += (long)u * b1_ustride;
    bias1 += (long)u * bias1_ustride;
    B2    += (long)u * b2_ustride;
    bias2 += (long)u * bias2_ustride;

    __shared__ __align__(16) short lds[24576];   // 48 KB
    short* Aa = lds;            // [128][32] BK32 A-tile, buf 0
    short* Ab = lds + 4096;     // buf 1
    short* hs = lds + 8192;     // [128][128] h-slab

    const int tid = threadIdx.x, lane = tid & 63, wave = tid >> 6;
    const int wm = wave >> 2, wn = wave & 3;
    const int brow = blockIdx.x * 128;
    const int l15 = lane & 15, lq = lane >> 4;
    const int nkt = K1 >> 5;                     // BK=32 steps (even)

    // A staging: 8KB tile = 8 wave-chunks of 1KB; lane covers 16B at base+lane*16.
    const int arow  = wave * 16 + (lane >> 2);           // 0..127
    const int aslog = ((lane & 3) ^ ((lane >> 2) & 3)) * 8;  // pre-swizzled K-chunk (shorts)
    const int slotA = (lq ^ (l15 & 3)) * 8;              // read-side slot (shorts)

#define STAGE_A(ko, dst) \
    gload_lds16(A + (long)(brow + arow) * lda + (ko) + aslog, (dst) + wave * 512)

    f32x4 acc2[4][2];
#pragma unroll
    for (int i = 0; i < 4; ++i)
#pragma unroll
        for (int j = 0; j < 2; ++j) acc2[i][j] = (f32x4){0.f, 0.f, 0.f, 0.f};

    STAGE_A(0, Aa);

    for (int p = 0; p < 2; ++p) {
        f32x4 acc1[4][2];
#pragma unroll
        for (int i = 0; i < 4; ++i)
#pragma unroll
            for (int j = 0; j < 2; ++j) acc1[i][j] = (f32x4){0.f, 0.f, 0.f, 0.f};

        const short* B1p = B1 + (long)(p * 128 + wn * 32 + l15) * K1;

        for (int kt = 0; kt < nkt; kt += 2) {
            __syncthreads();                     // A(kt) landed; Ab(kt-1) reads done
            if (kt + 1 < nkt) STAGE_A((kt + 1) * 32, Ab);
            {
                s16x8 af[4], bfv[2];
#pragma unroll
                for (int i = 0; i < 4; ++i)
                    af[i] = *(const s16x8*)&Aa[(wm * 64 + i * 16 + l15) * 32 + slotA];
#pragma unroll
                for (int j = 0; j < 2; ++j)
                    bfv[j] = *(const s16x8*)(B1p + (long)j * 16 * K1 + kt * 32 + lq * 8);
#pragma unroll
                for (int i = 0; i < 4; ++i)
#pragma unroll
                    for (int j = 0; j < 2; ++j)
                        acc1[i][j] = __builtin_amdgcn_mfma_f32_16x16x32_bf16(bfv[j], af[i], acc1[i][j], 0, 0, 0);
            }
            __syncthreads();                     // A(kt+1) landed; Aa reads done
            if (kt + 2 < nkt) STAGE_A((kt + 2) * 32, Aa);
            {
                s16x8 af[4], bfv[2];
#pragma unroll
                for (int i = 0; i < 4; ++i)
                    af[i] = *(const s16x8*)&Ab[(wm * 64 + i * 16 + l15) * 32 + slotA];
#pragma unroll
                for (int j = 0; j < 2; ++j)
                    bfv[j] = *(const s16x8*)(B1p + (long)j * 16 * K1 + (kt + 1) * 32 + lq * 8);
#pragma unroll
                for (int i = 0; i < 4; ++i)
#pragma unroll
                    for (int j = 0; j < 2; ++j)
                        acc1[i][j] = __builtin_amdgcn_mfma_f32_16x16x32_bf16(bfv[j], af[i], acc1[i][j], 0, 0, 0);
            }
        }

        if (p == 0) STAGE_A(0, Aa);              // re-stage kt0 for slab 1; flight spans h-write+GEMM2

        // ---- h-write: relu(acc1 + b1) -> bf16 via cvt_pk -> hs (XOR-swizzled) ----
        {
            const int cbq = lq << 2;
#pragma unroll
            for (int j = 0; j < 2; ++j) {
                int cb = wn * 32 + j * 16 + cbq;
                f32x4 bv = *(const f32x4*)(bias1 + p * 128 + cb);
#pragma unroll
                for (int i = 0; i < 4; ++i) {
                    int node = wm * 64 + i * 16 + l15;
                    float t0 = fmaxf(acc1[i][j][0] + bv[0], 0.f);
                    float t1 = fmaxf(acc1[i][j][1] + bv[1], 0.f);
                    float t2 = fmaxf(acc1[i][j][2] + bv[2], 0.f);
                    float t3 = fmaxf(acc1[i][j][3] + bv[3], 0.f);
                    u32x2 hw; hw[0] = cvtpk(t0, t1); hw[1] = cvtpk(t2, t3);
                    *(u32x2*)&hs[node * 128 + (((cb >> 3) ^ (node & 7)) << 3) + (cb & 7)] = hw;
                }
            }
        }
        __syncthreads();                         // h visible to all waves

        // ---- GEMM2: direct W2 fragments, no barriers ----
        const short* B2p = B2 + (long)(wn * 32 + l15) * 256 + p * 128;
#pragma unroll
        for (int kt2 = 0; kt2 < 2; ++kt2) {
#pragma unroll
            for (int kk = 0; kk < 2; ++kk) {
                const int c = kt2 * 8 + kk * 4 + lq;
                s16x8 hf[4], wf[2];
#pragma unroll
                for (int i = 0; i < 4; ++i) {
                    int row = wm * 64 + i * 16 + l15;
                    hf[i] = *(const s16x8*)&hs[row * 128 + ((c ^ (row & 7)) << 3)];
                }
#pragma unroll
                for (int j = 0; j < 2; ++j)
                    wf[j] = *(const s16x8*)(B2p + (long)j * 16 * 256 + kt2 * 64 + kk * 32 + lq * 8);
#pragma unroll
                for (int i = 0; i < 4; ++i)
#pragma unroll
                    for (int j = 0; j < 2; ++j)
                        acc2[i][j] = __builtin_amdgcn_mfma_f32_16x16x32_bf16(wf[j], hf[i], acc2[i][j], 0, 0, 0);
            }
        }
        __syncthreads();                         // hs reads done (next slab h-write / epilogue)
    }
#undef STAGE_A

    // ---- epilogue ----
    const int cbq = lq << 2;
    if (OUTBF16) {
        short* Cs = hs;
#pragma unroll
        for (int j = 0; j < 2; ++j) {
            int cb = wn * 32 + j * 16 + cbq;
            f32x4 bv = *(const f32x4*)(bias2 + cb);
#pragma unroll
            for (int i = 0; i < 4; ++i) {
                int node = wm * 64 + i * 16 + l15;
                u32x2 ow;
                ow[0] = cvtpk(acc2[i][j][0] + bv[0], acc2[i][j][1] + bv[1]);
                ow[1] = cvtpk(acc2[i][j][2] + bv[2], acc2[i][j][3] + bv[3]);
                *(u32x2*)&Cs[node * 128 + (((cb >> 3) ^ (node & 7)) << 3) + (cb & 7)] = ow;
            }
        }
        __syncthreads();
        short* cbase = (short*)Cv + u * c_ustride + (long)brow * ldc;
#pragma unroll
        for (int p8 = 0; p8 < 4; ++p8) {
            int g = tid + p8 * 512;
            int row = g >> 4, ck = g & 15;
            s16x8 val = *(const s16x8*)&Cs[row * 128 + ((ck ^ (row & 7)) * 8)];
            *(s16x8*)(cbase + (long)row * ldc + ck * 8) = val;
        }
    } else {
        float* cbase = (float*)Cv + u * c_ustride;
#pragma unroll
        for (int j = 0; j < 2; ++j) {
            int cb = wn * 32 + j * 16 + cbq;
            f32x4 bv = *(const f32x4*)(bias2 + cb);
#pragma unroll
            for (int i = 0; i < 4; ++i) {
                int node = wm * 64 + i * 16 + l15;
                f32x4 o;
#pragma unroll
                for (int r = 0; r < 4; ++r) o[r] = acc2[i][j][r] + bv[r];
                *(f32x4*)&cbase[(long)(brow + node) * ldc + cb] = o;
            }
        }
    }
}

// ---------------- attention kernels ----------------

__global__ void scores_mfma_kernel(const short* __restrict__ qk, float* __restrict__ scores,
                                   int nc) {
    const int lane = threadIdx.x & 63;
    int gw = (blockIdx.x * blockDim.x + threadIdx.x) >> 6;
    int nw = (gridDim.x * blockDim.x) >> 6;
    const int npairs = nc >> 1;
    const int r = lane & 15, ks = lane >> 4;
    for (int p = gw; p < npairs; p += nw) {
        const long n0 = (long)p * 2;
        const short* qp = qk + (n0 + (r >> 3)) * 2048 + (r & 7) * 128 + ks * 8;
        const short* kp = qp + 1024;
        f32x4 acc = (f32x4){0.f, 0.f, 0.f, 0.f};
#pragma unroll
        for (int kt = 0; kt < 4; ++kt) {
            s16x8 a = *(const s16x8*)(qp + kt * 32);
            s16x8 b = *(const s16x8*)(kp + kt * 32);
            acc = __builtin_amdgcn_mfma_f32_16x16x32_bf16(a, b, acc, 0, 0, 0);
        }
        const int c = lane & 15, rr0 = (lane >> 4) * 4;
        if ((rr0 >> 3) == (c >> 3)) {
            float* o = scores + (n0 + (rr0 >> 3)) * 64 + (c & 7);
#pragma unroll
            for (int reg = 0; reg < 4; ++reg)
                o[((rr0 & 7) + reg) * 8] = acc[reg] * 0.08838834764831845f;
        }
    }
}

__global__ void segstats1_kernel(const float* __restrict__ scores, const int* __restrict__ batch,
                                 float* __restrict__ pm, float* __restrict__ ps) {
    const int g = blockIdx.x, sl = blockIdx.y;
    int lo = 0, hi = N_NODES;
    while (lo < hi) { int mid = (lo + hi) >> 1; if (batch[mid] < g) lo = mid + 1; else hi = mid; }
    const int start = lo;
    hi = N_NODES;
    while (lo < hi) { int mid = (lo + hi) >> 1; if (batch[mid] <= g) lo = mid + 1; else hi = mid; }
    const int end = lo;
    const int len = end - start;
    const int s0 = start + (len * sl) / 8;
    const int s1 = start + (len * (sl + 1)) / 8;

    const int e = threadIdx.x & 63, sub = threadIdx.x >> 6;
    __shared__ float red[4][64];
    float m = -1e30f;
    for (int n = s0 + sub; n < s1; n += 4)
        m = fmaxf(m, scores[(long)n * 64 + e]);
    red[sub][e] = m;
    __syncthreads();
    m = fmaxf(fmaxf(red[0][e], red[1][e]), fmaxf(red[2][e], red[3][e]));
    __syncthreads();
    float s = 0.f;
    for (int n = s0 + sub; n < s1; n += 4)
        s += expf(scores[(long)n * 64 + e] - m);
    red[sub][e] = s;
    __syncthreads();
    if (sub == 0) {
        int idx = (g * 8 + sl) * 64 + e;
        pm[idx] = m;
        ps[idx] = red[0][e] + red[1][e] + red[2][e] + red[3][e];
    }
}

__global__ void segstats2_kernel(const float* __restrict__ pm, const float* __restrict__ ps,
                                 float* __restrict__ segm, float* __restrict__ segdinv) {
    const int g = blockIdx.x, e = threadIdx.x;   // 64 threads
    float M = -1e30f;
#pragma unroll
    for (int sl = 0; sl < 8; ++sl)
        M = fmaxf(M, pm[(g * 8 + sl) * 64 + e]);
    float den = 1e-16f;
#pragma unroll
    for (int sl = 0; sl < 8; ++sl) {
        int idx = (g * 8 + sl) * 64 + e;
        den += ps[idx] * expf(pm[idx] - M);
    }
    segm[g * 64 + e]    = M;
    segdinv[g * 64 + e] = 1.f / den;
}

__global__ void pv_kernel(const short* __restrict__ v, short* __restrict__ sout,
                          const float* __restrict__ scores, const int* __restrict__ batch,
                          const float* __restrict__ segm, const float* __restrict__ segdinv,
                          int n0) {
    __shared__ float aw[16][64];
    const int t = threadIdx.x;
    const int nodeL0 = blockIdx.x * 16;
    {
        int j0 = t * 4;
        int nl = j0 >> 6, e0 = j0 & 63;
        int n = n0 + nodeL0 + nl;
        int b = batch[n];
        f32x4 sc = *(const f32x4*)(scores + (long)n * 64 + e0);
#pragma unroll
        for (int i = 0; i < 4; ++i)
            aw[nl][e0 + i] = expf(sc[i] - segm[b * 64 + e0 + i]) * segdinv[b * 64 + e0 + i];
    }
    __syncthreads();
    const int nl = t >> 4;
    const int ec = (t & 15) * 8;
    const long nloc = nodeL0 + nl;
    const short* vp = v + nloc * 1024 + ec;
    float acc[8][8];
#pragma unroll
    for (int h = 0; h < 8; ++h)
#pragma unroll
        for (int j = 0; j < 8; ++j) acc[h][j] = 0.f;
#pragma unroll
    for (int g = 0; g < 8; ++g) {
        s16x8 vv = *(const s16x8*)(vp + g * 128);
        float vf[8];
#pragma unroll
        for (int j = 0; j < 8; ++j) vf[j] = bf2f((unsigned short)vv[j]);
#pragma unroll
        for (int h = 0; h < 8; ++h) {
            float wgt = aw[nl][h * 8 + g];
#pragma unroll
            for (int j = 0; j < 8; ++j) acc[h][j] += wgt * vf[j];
        }
    }
#pragma unroll
    for (int h = 0; h < 8; ++h) {
        union { s16x8 vv; unsigned uu[4]; } o;
#pragma unroll
        for (int jj = 0; jj < 4; ++jj)
            o.uu[jj] = cvtpk(acc[h][2 * jj], acc[h][2 * jj + 1]);
        *(s16x8*)(sout + nloc * 1024 + h * 128 + ec) = o.vv;
    }
}

// ---------------- launch ----------------

extern "C" void kernel_launch(void* const* d_in, const int* in_sizes, int n_in,
                              void* d_out, int out_size, void* d_ws, size_t ws_size,
                              hipStream_t stream) {
    const float* score = (const float*)d_in[0];
    const int*   batch = (const int*)d_in[2];
    const float* pos   = (const float*)d_in[3];
    const float* para  = (const float*)d_in[4];
    const float* Wq1 = (const float*)d_in[5];
    const float* bq1 = (const float*)d_in[6];
    const float* Wq2 = (const float*)d_in[7];
    const float* bq2 = (const float*)d_in[8];
    const float* Wk1 = (const float*)d_in[9];
    const float* bk1 = (const float*)d_in[10];
    const float* Wk2 = (const float*)d_in[11];
    const float* bk2 = (const float*)d_in[12];
    const float* Wv1 = (const float*)d_in[13];
    const float* bv1 = (const float*)d_in[14];
    const float* Wv2 = (const float*)d_in[15];
    const float* bv2 = (const float*)d_in[16];
    const float* Wo1 = (const float*)d_in[17];
    const float* bo1 = (const float*)d_in[18];
    const float* Wo2 = (const float*)d_in[19];
    const float* bo2 = (const float*)d_in[20];
    float* out = (float*)d_out;
    (void)in_sizes; (void)n_in; (void)out_size;

    // ---- persistent region (~57 MB) ----
    char* w = (char*)d_ws;
    short* sm     = (short*)w; w += (size_t)N_NODES * 256 * 2;
    float* scoresb= (float*)w; w += (size_t)N_NODES * 64 * 4;
    short* W1T    = (short*)w; w += (size_t)24 * 256 * 256 * 2;
    short* W2T    = (short*)w; w += (size_t)24 * 128 * 256 * 2;
    short* Wo1T   = (short*)w; w += (size_t)256 * 1024 * 2;
    short* Wo2T   = (short*)w; w += (size_t)128 * 256 * 2;
    float* b1cat  = (float*)w; w += 6144 * 4;
    float* b2cat  = (float*)w; w += 3072 * 4;
    float* bo2p   = (float*)w; w += 1024;
    float* segm   = (float*)w; w += 8192 * 4;
    float* segdi  = (float*)w; w += 8192 * 4;
    float* pm     = (float*)w; w += 65536 * 4;
    float* ps     = (float*)w; w += 65536 * 4;
    size_t persist = (size_t)(w - (char*)d_ws);
    size_t area = ws_size - persist;

    // phase A chunk: qk [NC,2048] bf16 (NC*4096 B)
    int NC = 32768;
    while (NC > 1024 && (size_t)NC * 4096 > area) NC >>= 1;
    const int nchunks = N_NODES / NC;
    short* X = (short*)w;                        // phase A: qk

    // ---- prep ----
    prep_sm_kernel<<<N_NODES * 256 / 4 / 256, 256, 0, stream>>>(score, pos, sm);
    transpose_all_kernel<<<2592, 256, 0, stream>>>(Wq1, Wk1, Wv1, Wq2, Wk2, Wv2, Wo1, Wo2,
                                                   W1T, W2T, Wo1T, Wo2T);
    prep_small_kernel<<<37, 256, 0, stream>>>(bq1, bk1, bv1, bq2, bk2, bv2, bo2, para,
                                              b1cat, b2cat, bo2p);

    // ---- phase A: fused q,k MLPs + scores (A/B: odd chunks use fused_mlpB) ----
    for (int c = 0; c < nchunks; ++c) {
        const int n0 = c * NC;
        if (c & 1) {
            fused_mlpB<true><<<dim3(NC / 128, 16), 512, 0, stream>>>(
                sm + (size_t)n0 * 256, 256, W1T, 65536, b1cat, 256,
                W2T, 32768, b2cat, 128, X, 2048, 128, 256);
        } else {
            fused_mlp<true><<<dim3(NC / 128, 16), 512, 0, stream>>>(
                sm + (size_t)n0 * 256, 256, W1T, 65536, b1cat, 256,
                W2T, 32768, b2cat, 128, X, 2048, 128, 256);
        }
        scores_mfma_kernel<<<NC / 8, 256, 0, stream>>>(X, scoresb + (size_t)n0 * 64, NC);
    }

    // ---- segment softmax stats ----
    segstats1_kernel<<<dim3(NSEG, 8), 256, 0, stream>>>(scoresb, batch, pm, ps);
    segstats2_kernel<<<NSEG, 64, 0, stream>>>(pm, ps, segm, segdi);

    // ---- phase B: v MLPs + PV (chunked) + ONE full-size out-MLP if ws allows ----
    const size_t sfull_bytes = (size_t)N_NODES * 2048;
    if (area >= sfull_bytes + (size_t)4096 * 2048) {
        int NCB = 16384;
        while ((size_t)NCB * 2048 + sfull_bytes > area) NCB >>= 1;
        short* sfull = (short*)w;
        short* v     = sfull + (size_t)N_NODES * 1024;
        for (int c = 0; c < N_NODES / NCB; ++c) {
            const int n0 = c * NCB;
            fused_mlp<true><<<dim3(NCB / 128, 8), 512, 0, stream>>>(
                sm + (size_t)n0 * 256, 256, W1T + 16 * 65536, 65536, b1cat + 16 * 256, 256,
                W2T + 16 * 32768, 32768, b2cat + 16 * 128, 128, v, 1024, 128, 256);
            pv_kernel<<<NCB / 16, 256, 0, stream>>>(v, sfull + (size_t)n0 * 1024,
                                                    scoresb, batch, segm, segdi, n0);
        }
        fused_mlp<false><<<dim3(N_NODES / 128, 1), 512, 0, stream>>>(
            sfull, 1024, Wo1T, 0, bo1, 0, Wo2T, 0, bo2p, 0, out, 128, 0, 1024);
    } else {
        int NCB = 32768;
        while (NCB > 1024 && (size_t)NCB * 4096 > area) NCB >>= 1;
        short* v = (short*)w;
        short* s = v + (size_t)NCB * 1024;
        for (int c = 0; c < N_NODES / NCB; ++c) {
            const int n0 = c * NCB;
            fused_mlp<true><<<dim3(NCB / 128, 8), 512, 0, stream>>>(
                sm + (size_t)n0 * 256, 256, W1T + 16 * 65536, 65536, b1cat + 16 * 256, 256,
                W2T + 16 * 32768, 32768, b2cat + 16 * 128, 128, v, 1024, 128, 256);
            pv_kernel<<<NCB / 16, 256, 0, stream>>>(v, s, scoresb, batch, segm, segdi, n0);
            fused_mlp<false><<<dim3(NCB / 128, 1), 512, 0, stream>>>(
                s, 1024, Wo1T, 0, bo1, 0, Wo2T, 0, bo2p, 0,
                out + (size_t)n0 * 128, 128, 0, 1024);
        }
    }
}

// Round 14
// 581.120 us; speedup vs baseline: 1.1561x; 1.1561x over previous
//
#include <hip/hip_runtime.h>

#define N_NODES 65536
#define NSEG    128

using s16x8 = __attribute__((ext_vector_type(8))) short;
using s16x4 = __attribute__((ext_vector_type(4))) short;
using f32x4 = __attribute__((ext_vector_type(4))) float;
using u32x2 = __attribute__((ext_vector_type(2))) unsigned;

__device__ __forceinline__ float bf2f(unsigned short s) {
    union { unsigned u; float f; } x; x.u = ((unsigned)s) << 16; return x.f;
}
__device__ __forceinline__ short f2bf(float f) {
    union { float f; unsigned u; } x; x.f = f;
    unsigned r = x.u + 0x7FFFu + ((x.u >> 16) & 1u);
    return (short)(r >> 16);
}
__device__ __forceinline__ unsigned cvtpk(float a, float b) {   // packed bf16(a)|bf16(b)<<16
    unsigned r;
    asm("v_cvt_pk_bf16_f32 %0, %1, %2" : "=v"(r) : "v"(a), "v"(b));
    return r;
}
__device__ __forceinline__ void gload_lds16(const void* g, void* lds) {
    __builtin_amdgcn_global_load_lds((const __attribute__((address_space(1))) void*)g,
                                     (__attribute__((address_space(3))) void*)lds, 16, 0, 0);
}

// ---------------- prep kernels ----------------

__global__ void prep_sm_kernel(const float* __restrict__ score, const float* __restrict__ pos,
                               short* __restrict__ sm) {
    int i = blockIdx.x * blockDim.x + threadIdx.x;
    int base = i * 4;
    f32x4 s = __builtin_nontemporal_load((const f32x4*)(score + base));
    f32x4 p = *(const f32x4*)(pos + (base & 255));
    u32x2 o;
    o[0] = cvtpk(s[0] + p[0], s[1] + p[1]);
    o[1] = cvtpk(s[2] + p[2], s[3] + p[3]);
    *(u32x2*)(sm + base) = o;
}

// all weight transposes in ONE launch. fp32 [R][C] -> bf16 [C][R] tiles of 32x32.
__global__ void transpose_all_kernel(const float* __restrict__ Wq1, const float* __restrict__ Wk1,
                                     const float* __restrict__ Wv1, const float* __restrict__ Wq2,
                                     const float* __restrict__ Wk2, const float* __restrict__ Wv2,
                                     const float* __restrict__ Wo1, const float* __restrict__ Wo2,
                                     short* __restrict__ W1T, short* __restrict__ W2T,
                                     short* __restrict__ Wo1T, short* __restrict__ Wo2T) {
    int t = blockIdx.x;
    const float* in; short* out; int R, C, tx, ty;
    if (t < 1536) {            // W1: 24 units, 256x256, 8x8 tiles
        int u = t >> 6, rem = t & 63;
        const float* s = (u < 8) ? Wq1 : (u < 16) ? Wk1 : Wv1;
        in = s + (long)(u & 7) * 65536; out = W1T + (long)u * 65536;
        R = 256; C = 256; tx = rem & 7; ty = rem >> 3;
    } else if (t < 2304) {     // W2: 24 units, 256x128, 4x8 tiles
        int t2 = t - 1536, u = t2 >> 5, rem = t2 & 31;
        const float* s = (u < 8) ? Wq2 : (u < 16) ? Wk2 : Wv2;
        in = s + (long)(u & 7) * 32768; out = W2T + (long)u * 32768;
        R = 256; C = 128; tx = rem & 3; ty = rem >> 2;
    } else if (t < 2560) {     // Wo1: 1024x256, 8x32 tiles
        int t3 = t - 2304;
        in = Wo1; out = Wo1T; R = 1024; C = 256; tx = t3 & 7; ty = t3 >> 3;
    } else {                   // Wo2: 256x128, 4x8 tiles
        int t4 = t - 2560;
        in = Wo2; out = Wo2T; R = 256; C = 128; tx = t4 & 3; ty = t4 >> 2;
    }
    __shared__ float tbuf[32][33];
    const int c0 = tx * 32, r0 = ty * 32;
    const int lx = threadIdx.x & 31, ly = threadIdx.x >> 5;
#pragma unroll
    for (int i = 0; i < 32; i += 8)
        tbuf[ly + i][lx] = in[(long)(r0 + ly + i) * C + c0 + lx];
    __syncthreads();
#pragma unroll
    for (int i = 0; i < 32; i += 8)
        out[(long)(c0 + ly + i) * R + r0 + lx] = f2bf(tbuf[lx][ly + i]);
}

__global__ void prep_small_kernel(const float* __restrict__ bq1, const float* __restrict__ bk1,
                                  const float* __restrict__ bv1, const float* __restrict__ bq2,
                                  const float* __restrict__ bk2, const float* __restrict__ bv2,
                                  const float* __restrict__ bo2, const float* __restrict__ para,
                                  float* __restrict__ b1cat, float* __restrict__ b2cat,
                                  float* __restrict__ bo2p) {
    int i = blockIdx.x * blockDim.x + threadIdx.x;
    if (i < 6144) {
        int u = i >> 8, j = i & 255;
        const float* s = (u < 8) ? (bq1 + u * 256 + j)
                       : (u < 16) ? (bk1 + (u - 8) * 256 + j)
                                  : (bv1 + (u - 16) * 256 + j);
        b1cat[i] = *s;
    } else if (i < 9216) {
        int ii = i - 6144;
        int u = ii >> 7, j = ii & 127;
        const float* s = (u < 8) ? (bq2 + u * 128 + j)
                       : (u < 16) ? (bk2 + (u - 8) * 128 + j)
                                  : (bv2 + (u - 16) * 128 + j);
        b2cat[ii] = *s;
    } else if (i < 9344) {
        int e = i - 9216;
        bo2p[e] = bo2[e] + para[e];
    }
}

// ------- fused 2-layer MLP; 512 threads (8 waves) on a 128x128 tile, 48 KB LDS -------
// C_u[M,128] = (relu(A[M,K1] @ B1_u^T[256,K1] + b1_u)) @ B2_u^T[128,256] + b2_u
// Envelope (r11/r12/r13 lessons): LDS <= 48KB AND arch+acc VGPR <= ~128, else
// occupancy halves and any structural gain is lost. W2 prefetch overlaps h-write.
// MFMA operands SWAPPED (mfma(b,a)): value(lane,reg) = D[node=l15][col=lq*4+reg]
// -> b64 LDS writes / 16B coalesced stores. bf16 converts via v_cvt_pk_bf16_f32.

template <bool OUTBF16>
__global__ __launch_bounds__(512, 2)
void fused_mlp(const short* __restrict__ A, int lda,
               const short* __restrict__ B1, long b1_ustride,    // [256, K1]
               const float* __restrict__ bias1, int bias1_ustride,
               const short* __restrict__ B2, long b2_ustride,    // [128, 256]
               const float* __restrict__ bias2, int bias2_ustride,
               void* __restrict__ Cv, int ldc, long c_ustride, int K1) {
    const int u = blockIdx.y;
    B1    += (long)u * b1_ustride;
    bias1 += (long)u * bias1_ustride;
    B2    += (long)u * b2_ustride;
    bias2 += (long)u * bias2_ustride;

    __shared__ __align__(16) short lds[24576];   // 48 KB
    short* Bs = lds;            // [128][64] W-tile — disjoint from hs
    short* As = lds + 8192;     // [128][64] A-tile (aliased by hs)
    short* hs = lds + 8192;     // [128][128] h-slab, chunk-XOR swizzled

    const int tid = threadIdx.x, lane = tid & 63, wave = tid >> 6;   // 8 waves
    const int wm = wave >> 2;          // node half
    const int wn = wave & 3;           // 32-col quarter
    const int brow = blockIdx.x * 128;

    const int lrow = lane >> 3;
    const int schk = ((lane & 7) ^ lrow) * 8;
    const int nkt1 = K1 >> 6;
    const int l15 = lane & 15, lq = lane >> 4;

    f32x4 acc2[4][2];
#pragma unroll
    for (int i = 0; i < 4; ++i)
#pragma unroll
        for (int j = 0; j < 2; ++j) acc2[i][j] = (f32x4){0.f, 0.f, 0.f, 0.f};

    for (int p = 0; p < 2; ++p) {
        f32x4 acc1[4][2];
#pragma unroll
        for (int i = 0; i < 4; ++i)
#pragma unroll
            for (int j = 0; j < 2; ++j) acc1[i][j] = (f32x4){0.f, 0.f, 0.f, 0.f};

        for (int kt = 0; kt < nkt1; ++kt) {
            __syncthreads();
            const int ko = kt * 64;
#pragma unroll
            for (int i = 0; i < 2; ++i) {
                int cch = wave * 2 + i;
                int r = cch * 8 + lrow;
                gload_lds16(A  + (long)(brow + r) * lda + ko + schk, &As[cch * 512]);
                gload_lds16(B1 + (long)(p * 128 + r) * K1 + ko + schk, &Bs[cch * 512]);
            }
            __syncthreads();
#pragma unroll
            for (int kk = 0; kk < 2; ++kk) {
                const int slot = (((kk * 4) + lq) ^ (lane & 7)) * 8;
                s16x8 af[4], bfv[2];
#pragma unroll
                for (int i = 0; i < 4; ++i)
                    af[i] = *(const s16x8*)&As[(wm * 64 + i * 16 + l15) * 64 + slot];
#pragma unroll
                for (int j = 0; j < 2; ++j)
                    bfv[j] = *(const s16x8*)&Bs[(wn * 32 + j * 16 + l15) * 64 + slot];
#pragma unroll
                for (int i = 0; i < 4; ++i)
#pragma unroll
                    for (int j = 0; j < 2; ++j)
                        acc1[i][j] = __builtin_amdgcn_mfma_f32_16x16x32_bf16(bfv[j], af[i], acc1[i][j], 0, 0, 0);
            }
        }

        __syncthreads();      // GEMM1 reads done

        // prefetch W2 first half-tile (async DMA) — overlaps the h-write VALU below
#pragma unroll
        for (int i = 0; i < 2; ++i) {
            int cch = wave * 2 + i;
            int r = cch * 8 + lrow;
            gload_lds16(B2 + (long)r * 256 + p * 128 + schk, &Bs[cch * 512]);
        }

        // ---- h-write: relu(acc1 + b1) -> bf16 via cvt_pk -> hs (XOR-swizzled) ----
        {
            const int cbq = lq << 2;
#pragma unroll
            for (int j = 0; j < 2; ++j) {
                int cb = wn * 32 + j * 16 + cbq;
                f32x4 bv = *(const f32x4*)(bias1 + p * 128 + cb);
#pragma unroll
                for (int i = 0; i < 4; ++i) {
                    int node = wm * 64 + i * 16 + l15;
                    float t0 = fmaxf(acc1[i][j][0] + bv[0], 0.f);
                    float t1 = fmaxf(acc1[i][j][1] + bv[1], 0.f);
                    float t2 = fmaxf(acc1[i][j][2] + bv[2], 0.f);
                    float t3 = fmaxf(acc1[i][j][3] + bv[3], 0.f);
                    u32x2 hw; hw[0] = cvtpk(t0, t1); hw[1] = cvtpk(t2, t3);
                    *(u32x2*)&hs[node * 128 + (((cb >> 3) ^ (node & 7)) << 3) + (cb & 7)] = hw;
                }
            }
        }

#pragma unroll
        for (int kt2 = 0; kt2 < 2; ++kt2) {
            __syncthreads();                     // h visible + W2 tile staged
#pragma unroll
            for (int kk = 0; kk < 2; ++kk) {
                const int slotb = (((kk * 4) + lq) ^ (lane & 7)) * 8;
                s16x8 hf[4], wf[2];
#pragma unroll
                for (int i = 0; i < 4; ++i) {
                    int row = wm * 64 + i * 16 + l15;
                    int c = kt2 * 8 + kk * 4 + lq;
                    hf[i] = *(const s16x8*)&hs[row * 128 + ((c ^ (row & 7)) << 3)];
                }
#pragma unroll
                for (int j = 0; j < 2; ++j)
                    wf[j] = *(const s16x8*)&Bs[(wn * 32 + j * 16 + l15) * 64 + slotb];
#pragma unroll
                for (int i = 0; i < 4; ++i)
#pragma unroll
                    for (int j = 0; j < 2; ++j)
                        acc2[i][j] = __builtin_amdgcn_mfma_f32_16x16x32_bf16(wf[j], hf[i], acc2[i][j], 0, 0, 0);
            }
            if (kt2 == 0) {
                __syncthreads();                 // Bs reads done; stage second W2 half-tile
#pragma unroll
                for (int i = 0; i < 2; ++i) {
                    int cch = wave * 2 + i;
                    int r = cch * 8 + lrow;
                    gload_lds16(B2 + (long)r * 256 + p * 128 + 64 + schk, &Bs[cch * 512]);
                }
            }
        }
    }

    // ---- epilogue: + b2; lane holds node=l15(+16i+64wm), cols cb..cb+3 ----
    const int cbq = lq << 2;
    if (OUTBF16) {
        __syncthreads();
        short* Cs = hs;
#pragma unroll
        for (int j = 0; j < 2; ++j) {
            int cb = wn * 32 + j * 16 + cbq;
            f32x4 bv = *(const f32x4*)(bias2 + cb);
#pragma unroll
            for (int i = 0; i < 4; ++i) {
                int node = wm * 64 + i * 16 + l15;
                u32x2 ow;
                ow[0] = cvtpk(acc2[i][j][0] + bv[0], acc2[i][j][1] + bv[1]);
                ow[1] = cvtpk(acc2[i][j][2] + bv[2], acc2[i][j][3] + bv[3]);
                *(u32x2*)&Cs[node * 128 + (((cb >> 3) ^ (node & 7)) << 3) + (cb & 7)] = ow;
            }
        }
        __syncthreads();
        short* cbase = (short*)Cv + u * c_ustride + (long)brow * ldc;
#pragma unroll
        for (int p8 = 0; p8 < 4; ++p8) {
            int g = tid + p8 * 512;
            int row = g >> 4, ck = g & 15;
            s16x8 val = *(const s16x8*)&Cs[row * 128 + ((ck ^ (row & 7)) * 8)];
            *(s16x8*)(cbase + (long)row * ldc + ck * 8) = val;
        }
    } else {
        float* cbase = (float*)Cv + u * c_ustride;
#pragma unroll
        for (int j = 0; j < 2; ++j) {
            int cb = wn * 32 + j * 16 + cbq;
            f32x4 bv = *(const f32x4*)(bias2 + cb);
#pragma unroll
            for (int i = 0; i < 4; ++i) {
                int node = wm * 64 + i * 16 + l15;
                f32x4 o;
#pragma unroll
                for (int r = 0; r < 4; ++r) o[r] = acc2[i][j][r] + bv[r];
                *(f32x4*)&cbase[(long)(brow + node) * ldc + cb] = o;
            }
        }
    }
}

// ---------------- attention kernels ----------------

__global__ void scores_mfma_kernel(const short* __restrict__ qk, float* __restrict__ scores,
                                   int nc) {
    const int lane = threadIdx.x & 63;
    int gw = (blockIdx.x * blockDim.x + threadIdx.x) >> 6;
    int nw = (gridDim.x * blockDim.x) >> 6;
    const int npairs = nc >> 1;
    const int r = lane & 15, ks = lane >> 4;
    for (int p = gw; p < npairs; p += nw) {
        const long n0 = (long)p * 2;
        const short* qp = qk + (n0 + (r >> 3)) * 2048 + (r & 7) * 128 + ks * 8;
        const short* kp = qp + 1024;
        f32x4 acc = (f32x4){0.f, 0.f, 0.f, 0.f};
#pragma unroll
        for (int kt = 0; kt < 4; ++kt) {
            s16x8 a = *(const s16x8*)(qp + kt * 32);
            s16x8 b = *(const s16x8*)(kp + kt * 32);
            acc = __builtin_amdgcn_mfma_f32_16x16x32_bf16(a, b, acc, 0, 0, 0);
        }
        const int c = lane & 15, rr0 = (lane >> 4) * 4;
        if ((rr0 >> 3) == (c >> 3)) {
            float* o = scores + (n0 + (rr0 >> 3)) * 64 + (c & 7);
#pragma unroll
            for (int reg = 0; reg < 4; ++reg)
                o[((rr0 & 7) + reg) * 8] = acc[reg] * 0.08838834764831845f;
        }
    }
}

__global__ void segstats1_kernel(const float* __restrict__ scores, const int* __restrict__ batch,
                                 float* __restrict__ pm, float* __restrict__ ps) {
    const int g = blockIdx.x, sl = blockIdx.y;
    int lo = 0, hi = N_NODES;
    while (lo < hi) { int mid = (lo + hi) >> 1; if (batch[mid] < g) lo = mid + 1; else hi = mid; }
    const int start = lo;
    hi = N_NODES;
    while (lo < hi) { int mid = (lo + hi) >> 1; if (batch[mid] <= g) lo = mid + 1; else hi = mid; }
    const int end = lo;
    const int len = end - start;
    const int s0 = start + (len * sl) / 8;
    const int s1 = start + (len * (sl + 1)) / 8;

    const int e = threadIdx.x & 63, sub = threadIdx.x >> 6;
    __shared__ float red[4][64];
    float m = -1e30f;
    for (int n = s0 + sub; n < s1; n += 4)
        m = fmaxf(m, scores[(long)n * 64 + e]);
    red[sub][e] = m;
    __syncthreads();
    m = fmaxf(fmaxf(red[0][e], red[1][e]), fmaxf(red[2][e], red[3][e]));
    __syncthreads();
    float s = 0.f;
    for (int n = s0 + sub; n < s1; n += 4)
        s += expf(scores[(long)n * 64 + e] - m);
    red[sub][e] = s;
    __syncthreads();
    if (sub == 0) {
        int idx = (g * 8 + sl) * 64 + e;
        pm[idx] = m;
        ps[idx] = red[0][e] + red[1][e] + red[2][e] + red[3][e];
    }
}

__global__ void segstats2_kernel(const float* __restrict__ pm, const float* __restrict__ ps,
                                 float* __restrict__ segm, float* __restrict__ segdinv) {
    const int g = blockIdx.x, e = threadIdx.x;   // 64 threads
    float M = -1e30f;
#pragma unroll
    for (int sl = 0; sl < 8; ++sl)
        M = fmaxf(M, pm[(g * 8 + sl) * 64 + e]);
    float den = 1e-16f;
#pragma unroll
    for (int sl = 0; sl < 8; ++sl) {
        int idx = (g * 8 + sl) * 64 + e;
        den += ps[idx] * expf(pm[idx] - M);
    }
    segm[g * 64 + e]    = M;
    segdinv[g * 64 + e] = 1.f / den;
}

__global__ void pv_kernel(const short* __restrict__ v, short* __restrict__ sout,
                          const float* __restrict__ scores, const int* __restrict__ batch,
                          const float* __restrict__ segm, const float* __restrict__ segdinv,
                          int n0) {
    __shared__ float aw[16][64];
    const int t = threadIdx.x;
    const int nodeL0 = blockIdx.x * 16;
    {
        int j0 = t * 4;
        int nl = j0 >> 6, e0 = j0 & 63;
        int n = n0 + nodeL0 + nl;
        int b = batch[n];
        f32x4 sc = *(const f32x4*)(scores + (long)n * 64 + e0);
#pragma unroll
        for (int i = 0; i < 4; ++i)
            aw[nl][e0 + i] = expf(sc[i] - segm[b * 64 + e0 + i]) * segdinv[b * 64 + e0 + i];
    }
    __syncthreads();
    const int nl = t >> 4;
    const int ec = (t & 15) * 8;
    const long nloc = nodeL0 + nl;
    const short* vp = v + nloc * 1024 + ec;
    float acc[8][8];
#pragma unroll
    for (int h = 0; h < 8; ++h)
#pragma unroll
        for (int j = 0; j < 8; ++j) acc[h][j] = 0.f;
#pragma unroll
    for (int g = 0; g < 8; ++g) {
        s16x8 vv = *(const s16x8*)(vp + g * 128);
        float vf[8];
#pragma unroll
        for (int j = 0; j < 8; ++j) vf[j] = bf2f((unsigned short)vv[j]);
#pragma unroll
        for (int h = 0; h < 8; ++h) {
            float wgt = aw[nl][h * 8 + g];
#pragma unroll
            for (int j = 0; j < 8; ++j) acc[h][j] += wgt * vf[j];
        }
    }
#pragma unroll
    for (int h = 0; h < 8; ++h) {
        union { s16x8 vv; unsigned uu[4]; } o;
#pragma unroll
        for (int jj = 0; jj < 4; ++jj)
            o.uu[jj] = cvtpk(acc[h][2 * jj], acc[h][2 * jj + 1]);
        *(s16x8*)(sout + nloc * 1024 + h * 128 + ec) = o.vv;
    }
}

// ---------------- launch ----------------

extern "C" void kernel_launch(void* const* d_in, const int* in_sizes, int n_in,
                              void* d_out, int out_size, void* d_ws, size_t ws_size,
                              hipStream_t stream) {
    const float* score = (const float*)d_in[0];
    const int*   batch = (const int*)d_in[2];
    const float* pos   = (const float*)d_in[3];
    const float* para  = (const float*)d_in[4];
    const float* Wq1 = (const float*)d_in[5];
    const float* bq1 = (const float*)d_in[6];
    const float* Wq2 = (const float*)d_in[7];
    const float* bq2 = (const float*)d_in[8];
    const float* Wk1 = (const float*)d_in[9];
    const float* bk1 = (const float*)d_in[10];
    const float* Wk2 = (const float*)d_in[11];
    const float* bk2 = (const float*)d_in[12];
    const float* Wv1 = (const float*)d_in[13];
    const float* bv1 = (const float*)d_in[14];
    const float* Wv2 = (const float*)d_in[15];
    const float* bv2 = (const float*)d_in[16];
    const float* Wo1 = (const float*)d_in[17];
    const float* bo1 = (const float*)d_in[18];
    const float* Wo2 = (const float*)d_in[19];
    const float* bo2 = (const float*)d_in[20];
    float* out = (float*)d_out;
    (void)in_sizes; (void)n_in; (void)out_size;

    // ---- persistent region (~57 MB) ----
    char* w = (char*)d_ws;
    short* sm     = (short*)w; w += (size_t)N_NODES * 256 * 2;
    float* scoresb= (float*)w; w += (size_t)N_NODES * 64 * 4;
    short* W1T    = (short*)w; w += (size_t)24 * 256 * 256 * 2;
    short* W2T    = (short*)w; w += (size_t)24 * 128 * 256 * 2;
    short* Wo1T   = (short*)w; w += (size_t)256 * 1024 * 2;
    short* Wo2T   = (short*)w; w += (size_t)128 * 256 * 2;
    float* b1cat  = (float*)w; w += 6144 * 4;
    float* b2cat  = (float*)w; w += 3072 * 4;
    float* bo2p   = (float*)w; w += 1024;
    float* segm   = (float*)w; w += 8192 * 4;
    float* segdi  = (float*)w; w += 8192 * 4;
    float* pm     = (float*)w; w += 65536 * 4;
    float* ps     = (float*)w; w += 65536 * 4;
    size_t persist = (size_t)(w - (char*)d_ws);
    size_t area = ws_size - persist;

    // phase A chunk: qk [NC,2048] bf16 (NC*4096 B)
    int NC = 32768;
    while (NC > 1024 && (size_t)NC * 4096 > area) NC >>= 1;
    const int nchunks = N_NODES / NC;
    short* X = (short*)w;                        // phase A: qk

    // ---- prep ----
    prep_sm_kernel<<<N_NODES * 256 / 4 / 256, 256, 0, stream>>>(score, pos, sm);
    transpose_all_kernel<<<2592, 256, 0, stream>>>(Wq1, Wk1, Wv1, Wq2, Wk2, Wv2, Wo1, Wo2,
                                                   W1T, W2T, Wo1T, Wo2T);
    prep_small_kernel<<<37, 256, 0, stream>>>(bq1, bk1, bv1, bq2, bk2, bv2, bo2, para,
                                              b1cat, b2cat, bo2p);

    // ---- phase A: fused q,k MLPs + scores ----
    for (int c = 0; c < nchunks; ++c) {
        const int n0 = c * NC;
        fused_mlp<true><<<dim3(NC / 128, 16), 512, 0, stream>>>(
            sm + (size_t)n0 * 256, 256, W1T, 65536, b1cat, 256,
            W2T, 32768, b2cat, 128, X, 2048, 128, 256);
        scores_mfma_kernel<<<NC / 8, 256, 0, stream>>>(X, scoresb + (size_t)n0 * 64, NC);
    }

    // ---- segment softmax stats ----
    segstats1_kernel<<<dim3(NSEG, 8), 256, 0, stream>>>(scoresb, batch, pm, ps);
    segstats2_kernel<<<NSEG, 64, 0, stream>>>(pm, ps, segm, segdi);

    // ---- phase B: v MLPs + PV (chunked) + ONE full-size out-MLP if ws allows ----
    const size_t sfull_bytes = (size_t)N_NODES * 2048;
    if (area >= sfull_bytes + (size_t)4096 * 2048) {
        int NCB = 16384;
        while ((size_t)NCB * 2048 + sfull_bytes > area) NCB >>= 1;
        short* sfull = (short*)w;
        short* v     = sfull + (size_t)N_NODES * 1024;
        for (int c = 0; c < N_NODES / NCB; ++c) {
            const int n0 = c * NCB;
            fused_mlp<true><<<dim3(NCB / 128, 8), 512, 0, stream>>>(
                sm + (size_t)n0 * 256, 256, W1T + 16 * 65536, 65536, b1cat + 16 * 256, 256,
                W2T + 16 * 32768, 32768, b2cat + 16 * 128, 128, v, 1024, 128, 256);
            pv_kernel<<<NCB / 16, 256, 0, stream>>>(v, sfull + (size_t)n0 * 1024,
                                                    scoresb, batch, segm, segdi, n0);
        }
        fused_mlp<false><<<dim3(N_NODES / 128, 1), 512, 0, stream>>>(
            sfull, 1024, Wo1T, 0, bo1, 0, Wo2T, 0, bo2p, 0, out, 128, 0, 1024);
    } else {
        int NCB = 32768;
        while (NCB > 1024 && (size_t)NCB * 4096 > area) NCB >>= 1;
        short* v = (short*)w;
        short* s = v + (size_t)NCB * 1024;
        for (int c = 0; c < N_NODES / NCB; ++c) {
            const int n0 = c * NCB;
            fused_mlp<true><<<dim3(NCB / 128, 8), 512, 0, stream>>>(
                sm + (size_t)n0 * 256, 256, W1T + 16 * 65536, 65536, b1cat + 16 * 256, 256,
                W2T + 16 * 32768, 32768, b2cat + 16 * 128, 128, v, 1024, 128, 256);
            pv_kernel<<<NCB / 16, 256, 0, stream>>>(v, s, scoresb, batch, segm, segdi, n0);
            fused_mlp<false><<<dim3(NCB / 128, 1), 512, 0, stream>>>(
                s, 1024, Wo1T, 0, bo1, 0, Wo2T, 0, bo2p, 0,
                out + (size_t)n0 * 128, 128, 0, 1024);
        }
    }
}